// Round 6
// baseline (593.876 us; speedup 1.0000x reference)
//
#include <hip/hip_runtime.h>
#include <cstdint>
#include <cstddef>

#define DD 2048
#define LL 2048
#define BB 4
#define MM (BB * LL) // 8192
#define NN 6144      // fused q|k|v output columns

typedef __bf16 bf16;
typedef __bf16 bf16x8 __attribute__((ext_vector_type(8)));
typedef __bf16 bf16x4 __attribute__((ext_vector_type(4)));
typedef __bf16 bf16x2 __attribute__((ext_vector_type(2)));
typedef float f32x4 __attribute__((ext_vector_type(4)));

// ---------------------------------------------------------------------------
// async global -> LDS, 16B per lane (wave-uniform base + lane*16 layout)
// ---------------------------------------------------------------------------
__device__ __forceinline__ void gload16(const void* g, void* l) {
    __builtin_amdgcn_global_load_lds(
        (const __attribute__((address_space(1))) void*)g,
        (__attribute__((address_space(3))) void*)l, 16, 0, 0);
}

// ---------------------------------------------------------------------------
// fused fp32 -> bf16 conversion for all 5 tensors (1 launch instead of 5).
// ---------------------------------------------------------------------------
__global__ __launch_bounds__(256) void cvt_all(
    const float* __restrict__ u, const float* __restrict__ wq,
    const float* __restrict__ wk, const float* __restrict__ wv,
    const float* __restrict__ wo, bf16* __restrict__ u_bf,
    bf16* __restrict__ wqkv, bf16* __restrict__ wo_bf) {
    const int blk = blockIdx.x;
    const float* s;
    bf16* d;
    int base;
    if (blk < 8192)       { s = u;  d = u_bf;            base = 0; }
    else if (blk < 10240) { s = wq; d = wqkv;            base = 8192; }
    else if (blk < 12288) { s = wk; d = wqkv + 4194304;  base = 10240; }
    else if (blk < 14336) { s = wv; d = wqkv + 8388608;  base = 12288; }
    else                  { s = wo; d = wo_bf;           base = 14336; }
    const int i = (blk - base) * 256 + threadIdx.x;
    const float4* sp = (const float4*)s + (size_t)i * 2;
    float4 a = sp[0], b = sp[1];
    bf16x8 o;
    o[0] = (bf16)a.x; o[1] = (bf16)a.y; o[2] = (bf16)a.z; o[3] = (bf16)a.w;
    o[4] = (bf16)b.x; o[5] = (bf16)b.y; o[6] = (bf16)b.z; o[7] = (bf16)b.w;
    *((bf16x8*)d + i) = o;
}

// ---------------------------------------------------------------------------
// 256x256 8-wave K-loop (BK=64, 2 LDS buffers = 128 KiB), within-tile
// register read-ahead: 2 barriers per K-tile (h0/h1 residency gates),
// counted vmcnt(4) (never 0 until last tile), counted lgkm waits left to
// the compiler (C++ ds_reads -> dependence-exact lgkmcnt(N)).
// ---------------------------------------------------------------------------
__device__ __forceinline__ void stage_half(const bf16* g, bf16* l, size_t rstep, int tid) {
    gload16(g, l + tid * 8);
    gload16(g + rstep, l + 4096 + tid * 8);
}

#define MFMA_BLK(AF, BQ, IOFF)                                                  \
    __builtin_amdgcn_s_setprio(1);                                              \
    _Pragma("unroll") for (int j = 0; j < 4; j++)                               \
        _Pragma("unroll") for (int i = 0; i < 4; i++)                           \
            acc[(IOFF) + i][j] = __builtin_amdgcn_mfma_f32_16x16x32_bf16(       \
                AF[i], BQ[j], acc[(IOFF) + i][j], 0, 0, 0);                     \
    __builtin_amdgcn_s_setprio(0);

template <int NT>
__device__ __forceinline__ void mma256_loop(const bf16* gA, const bf16* gB,
                                            int Kdim, bf16* lds,
                                            f32x4 (&acc)[8][4]) {
    const int tid = threadIdx.x;
    const int wave = tid >> 6, lane = tid & 63;
    const int wm = wave >> 2, wn = wave & 3;     // 2 x 4 wave grid
    const int fm = lane & 15, fg = lane >> 4;
    const size_t rstep = (size_t)128 * Kdim;
    const int koff = ((fg ^ ((fm >> 1) & 3)) << 3);
    const int aoff = (wm * 128 + fm) * 32 + koff;
    const int boff = (wn * 64 + fm) * 32 + koff;

    bf16* const A0 = lds;
    bf16* const B0 = lds + 32768;

#pragma unroll
    for (int i = 0; i < 8; i++)
#pragma unroll
        for (int j = 0; j < 4; j++) acc[i][j] = (f32x4){0.f, 0.f, 0.f, 0.f};

    stage_half(gA, A0, rstep, tid);
    stage_half(gB, B0, rstep, tid);
    stage_half(gA + 32, A0 + 8192, rstep, tid);
    stage_half(gB + 32, B0 + 8192, rstep, tid);

    bf16x8 af0[4], af1[4], bq0[4], bq1[4];

    for (int t = 0; t < NT; ++t) {
        const int c = t & 1;
        bf16* const Ac = A0 + c * 16384;
        bf16* const Bc = B0 + c * 16384;
        bf16* const An = A0 + (c ^ 1) * 16384;
        bf16* const Bn = B0 + (c ^ 1) * 16384;
        const bf16* a1 = gA + (t + 1) * 64;
        const bf16* b1 = gB + (t + 1) * 64;
        const bool st = (t + 1 < NT);

        // ---- h0 residency gate ----
        asm volatile("s_waitcnt vmcnt(4)" ::: "memory");
        asm volatile("s_barrier" ::: "memory");
#pragma unroll
        for (int i = 0; i < 4; i++) af0[i] = *(const bf16x8*)(Ac + aoff + i * 512);
#pragma unroll
        for (int j = 0; j < 4; j++) bq0[j] = *(const bf16x8*)(Bc + boff + j * 512);
        if (st) stage_half(a1, An, rstep, tid);
#pragma unroll
        for (int i = 0; i < 4; i++) af1[i] = *(const bf16x8*)(Ac + aoff + (i + 4) * 512);
        MFMA_BLK(af0, bq0, 0)
        if (st) stage_half(b1, Bn, rstep, tid);

        // ---- h1 residency gate ----
        if (st) { asm volatile("s_waitcnt vmcnt(4)" ::: "memory"); }
        else    { asm volatile("s_waitcnt vmcnt(0)" ::: "memory"); }
        asm volatile("s_barrier" ::: "memory");
#pragma unroll
        for (int i = 0; i < 4; i++) af0[i] = *(const bf16x8*)(Ac + 8192 + aoff + i * 512);
#pragma unroll
        for (int j = 0; j < 4; j++) bq1[j] = *(const bf16x8*)(Bc + 8192 + boff + j * 512);
        if (st) stage_half(a1 + 32, An + 8192, rstep, tid);
        MFMA_BLK(af1, bq0, 4)
#pragma unroll
        for (int i = 0; i < 4; i++) af1[i] = *(const bf16x8*)(Ac + 8192 + aoff + (i + 4) * 512);
        if (st) stage_half(b1 + 32, Bn + 8192, rstep, tid);
        MFMA_BLK(af0, bq1, 0)
        MFMA_BLK(af1, bq1, 4)
    }
}

// ---------------------------------------------------------------------------
// Fused QKV GEMM -> transposed bf16 output (6144, 8192).  (unchanged R5)
// ---------------------------------------------------------------------------
__global__ __launch_bounds__(512, 2) void gemm_qkv(const bf16* __restrict__ A,
                                                   const bf16* __restrict__ Bm,
                                                   const float* __restrict__ bqp,
                                                   const float* __restrict__ bkp,
                                                   const float* __restrict__ bvp,
                                                   bf16* __restrict__ CtOut) {
    __shared__ bf16 lds[65536];
    const int id = blockIdx.x;        // nwg = 768 = 8 XCD x (4m x 24n)
    const int xcd = id & 7, li = id >> 3;
    const int m0 = (xcd * 4 + (li & 3)) << 8;
    const int n0 = (li >> 2) << 8;

    const int tid = threadIdx.x;
    const int wave = tid >> 6, lane = tid & 63;
    const int srow = tid >> 2;
    const int skx = (((lane & 3) ^ ((lane >> 3) & 3)) << 3);
    const bf16* gA = A + (size_t)(m0 + srow) * DD + skx;
    const bf16* gB = Bm + (size_t)(n0 + srow) * DD + skx;

    f32x4 acc[8][4];
    mma256_loop<DD / 64>(gA, gB, DD, lds, acc);

    __syncthreads();
    const int wm = wave >> 2, wn = wave & 3;
    const int fm = lane & 15, fg = lane >> 4;
    const float* bp = (n0 < 2048) ? bqp : ((n0 < 4096) ? bkp : bvp);
    const int nb = n0 & 2047;
#pragma unroll
    for (int j = 0; j < 4; j++) {
        const int col = wn * 64 + j * 16 + fm;
        const float bvv = bp[nb + col];
        const int csw = (col & 7) << 3;
#pragma unroll
        for (int i = 0; i < 8; i++) {
            const int row = (wm * 128 + i * 16 + fg * 4) ^ csw;
            bf16x4 o;
#pragma unroll
            for (int r = 0; r < 4; r++) o[r] = (bf16)(acc[i][j][r] + bvv);
            *(bf16x4*)&lds[col * 256 + row] = o;
        }
    }
    __syncthreads();
    const int ccol = tid >> 5, chunk = tid & 31;
#pragma unroll
    for (int p = 0; p < 16; p++) {
        const int col = p * 16 + ccol;
        bf16x8 vv = *(const bf16x8*)&lds[col * 256 + ((chunk * 8) ^ ((col & 7) << 3))];
        *(bf16x8*)(CtOut + (size_t)(n0 + col) * MM + m0 + chunk * 8) = vv;
    }
}

// ---------------------------------------------------------------------------
// Output projection GEMM (row-major f32 out).  (unchanged R5)
// ---------------------------------------------------------------------------
__global__ __launch_bounds__(512, 2) void gemm_bt_f32(const bf16* __restrict__ A,
                                                      const bf16* __restrict__ Bm,
                                                      const float* __restrict__ bias,
                                                      float* __restrict__ C,
                                                      int Ndim, int Kdim) {
    __shared__ bf16 lds[65536];
    const int id = blockIdx.x;
    const int xcd = id & 7, li = id >> 3;
    const int m0 = (xcd * 4 + (li & 3)) << 8;
    const int n0 = (li >> 2) << 8;

    const int tid = threadIdx.x;
    const int wave = tid >> 6, lane = tid & 63;
    const int srow = tid >> 2;
    const int skx = (((lane & 3) ^ ((lane >> 3) & 3)) << 3);
    const bf16* gA = A + (size_t)(m0 + srow) * Kdim + skx;
    const bf16* gB = Bm + (size_t)(n0 + srow) * Kdim + skx;

    f32x4 acc[8][4];
    mma256_loop<DD / 64>(gA, gB, Kdim, lds, acc);

    const int wm = wave >> 2, wn = wave & 3;
    const int fm = lane & 15, fg = lane >> 4;
#pragma unroll
    for (int j = 0; j < 4; j++) {
        const int col = n0 + wn * 64 + j * 16 + fm;
        const float bvv = bias[col];
#pragma unroll
        for (int i = 0; i < 8; i++) {
#pragma unroll
            for (int r = 0; r < 4; r++) {
                const int row = m0 + wm * 128 + i * 16 + fg * 4 + r;
                C[(size_t)row * Ndim + col] = acc[i][j][r] + bvv;
            }
        }
    }
}

// ---------------------------------------------------------------------------
// Depthwise causal conv (width 3) on qT/kT rows + kv=conv(k)*v.  (unchanged)
// ---------------------------------------------------------------------------
__global__ __launch_bounds__(256) void dwconv_kv2(
    const bf16* __restrict__ qkvT,
    const float* __restrict__ cqw, const float* __restrict__ cqb,
    const float* __restrict__ ckw, const float* __restrict__ ckb,
    bf16* __restrict__ qcT, bf16* __restrict__ kvT) {
    const int bid = blockIdx.x;
    const int b = bid >> 11, d = bid & (DD - 1);
    const int tid = threadIdx.x;
    const int l = tid * 8;

    const bf16* qR = qkvT + (size_t)d * MM + b * LL;
    const bf16* kR = qkvT + (size_t)(2048 + d) * MM + b * LL;
    const bf16* vR = qkvT + (size_t)(4096 + d) * MM + b * LL;

    const float q0 = cqw[d * 3], q1 = cqw[d * 3 + 1], q2 = cqw[d * 3 + 2];
    const float k0 = ckw[d * 3], k1 = ckw[d * 3 + 1], k2 = ckw[d * 3 + 2];
    const float qb = cqb[d], kb = ckb[d];

    bf16x8 qx = *(const bf16x8*)(qR + l);
    bf16x8 kx = *(const bf16x8*)(kR + l);
    bf16x8 vx = *(const bf16x8*)(vR + l);

    float xq[10], xk[10];
    xq[0] = 0.f; xq[1] = 0.f; xk[0] = 0.f; xk[1] = 0.f;
    if (l >= 2) {
        bf16x2 qh = *(const bf16x2*)(qR + l - 2);
        bf16x2 kh = *(const bf16x2*)(kR + l - 2);
        xq[0] = (float)qh[0]; xq[1] = (float)qh[1];
        xk[0] = (float)kh[0]; xk[1] = (float)kh[1];
    }
#pragma unroll
    for (int c = 0; c < 8; c++) { xq[c + 2] = (float)qx[c]; xk[c + 2] = (float)kx[c]; }

    bf16x8 oq, okv;
#pragma unroll
    for (int c = 0; c < 8; c++) {
        float qc = q0 * xq[c] + q1 * xq[c + 1] + q2 * xq[c + 2] + qb;
        float kc = k0 * xk[c] + k1 * xk[c + 1] + k2 * xk[c + 2] + kb;
        oq[c] = (bf16)qc;
        okv[c] = (bf16)(kc * (float)vx[c]);
    }
    const size_t o = ((size_t)b * DD + d) * LL + l;
    *(bf16x8*)(qcT + o) = oq;
    *(bf16x8*)(kvT + o) = okv;
}

// ---------------------------------------------------------------------------
// Causal long conv + D-skip + q gating via Toeplitz MFMA.
// CHANGE (R6): A-fragment via 8 SHIFTED bf16 COPIES of the reversed kernel.
// Old inner loop rebuilt the Toeplitz A-frag each iteration with 8 scalar
// f32 ds_reads + 8 cvts (per-lane window start as = 2031-32it-n+8q has fixed
// alignment class r = (7-n)&7, so it can't vectorize from one array).
// New: krevA[r][x] = krev[x+r] (stride 2120 -> perfect bank-group spread);
// lane reads ONE aligned ds_read_b128 at krevA[r][as-r]:
//   krevA[r][as-r+j] = krev[as+j]  (as-r >= 0, as+7 <= 2062 < 2120).
// Removes 8 b32 + 8 cvt from every one of 64 iterations per wave.
// ---------------------------------------------------------------------------
#define KVS 2120
#define KAS 2120
__global__ __launch_bounds__(128, 2) void longconv_gate(
    const bf16* __restrict__ kvT, const bf16* __restrict__ qcT,
    const float* __restrict__ kern, const float* __restrict__ Dskip,
    bf16* __restrict__ ygT) {
    __shared__ bf16 kv_ls[4 * KVS];
    __shared__ bf16 krevA[8 * KAS]; // 8 shifted copies, 33.9 KB
    const int d = blockIdx.x;
    const int tid = threadIdx.x;

    // ---- zero krevA (vectorized, 2120 chunks of 8) + stage kv ----
    for (int c = tid; c < 2120; c += 128) {
        bf16x8 z = {};
        *(bf16x8*)&krevA[c * 8] = z;
    }
    {
        const int bb = tid >> 5, t32 = tid & 31;
#pragma unroll
        for (int c = 0; c < 8; ++c) {
            const int l = (c * 32 + t32) * 8;
            bf16x8 v = *(const bf16x8*)(kvT + ((size_t)bb * DD + d) * LL + l);
            *(bf16x8*)&kv_ls[KVS * bb + 48 + l] = v;
        }
        if (tid < 48) {
#pragma unroll
            for (int b2 = 0; b2 < 4; b2++) kv_ls[KVS * b2 + tid] = (bf16)0.f;
        } else if (tid < 72) {
#pragma unroll
            for (int b2 = 0; b2 < 4; b2++) kv_ls[KVS * b2 + 2048 + tid] = (bf16)0.f;
        }
    }
    __syncthreads(); // krevA zero complete before shifted-value writes

    // ---- fill 8 shifted copies: krevA[r][y-r] = krev[y] = kern[d][2047-y] ----
    {
        const float* kr = kern + (size_t)d * LL;
#pragma unroll
        for (int c = 0; c < 16; ++c) {
            const int y = c * 128 + tid;
            const bf16 v = (bf16)kr[2047 - y];
#pragma unroll
            for (int r = 0; r < 8; r++) {
                const int x = y - r;
                if (x >= 0) krevA[r * KAS + x] = v;
            }
        }
    }
    __syncthreads();

    const int lane = tid & 63;
    const int w = __builtin_amdgcn_readfirstlane(tid >> 6);
    const int n = lane & 15, q = lane >> 4;
    const int b = n & 3, pp = n >> 2;
    const int cB = KVS * b + 16 * pp + 8 * q;
    const int r = (7 - n) & 7;
    const int abase = r * KAS - r + 2031 - n + 8 * q; // + (-32it) each iter

    f32x4 acc[16];
#pragma unroll
    for (int s = 0; s < 16; s++) acc[s] = (f32x4){0.f, 0.f, 0.f, 0.f};

    for (int it = 0; it < 64; ++it) {
        const bf16x8 a = *(const bf16x8*)&krevA[abase - 32 * it];

        const int bbase = cB + 64 * w + 32 - 32 * it;
#pragma unroll
        for (int h = 0; h < 2; ++h) {
            bf16x8 bfr[8];
#pragma unroll
            for (int s8 = 0; s8 < 8; s8++) {
                const int s = h * 8 + s8;
                if (it <= 4 * s + 2 * w + 1)
                    bfr[s8] = *(const bf16x8*)&kv_ls[bbase + 128 * s];
            }
#pragma unroll
            for (int s8 = 0; s8 < 8; s8++) {
                const int s = h * 8 + s8;
                if (it <= 4 * s + 2 * w + 1)
                    acc[s] = __builtin_amdgcn_mfma_f32_16x16x32_bf16(
                        a, bfr[s8], acc[s], 0, 0, 0);
            }
        }
    }

    const float dsk = Dskip[d];
#pragma unroll
    for (int s = 0; s < 16; s++) {
        const int i = 2 * s + w;
        const int l = 64 * i + 16 * pp + 4 * q;
        const size_t gb = ((size_t)b * DD + d) * LL + l;
        bf16x4 qc4 = *(const bf16x4*)&qcT[gb];
        bf16x4 kv4 = *(const bf16x4*)&kv_ls[KVS * b + 48 + l];
        bf16x4 o;
#pragma unroll
        for (int rr = 0; rr < 4; rr++) {
            float val = (acc[s][rr] + (float)kv4[rr] * dsk) * (float)qc4[rr];
            o[rr] = (bf16)val;
        }
        *(bf16x4*)&ygT[gb] = o;
    }
}

// ---------------------------------------------------------------------------
// bf16 transpose (B, D, L) -> (B, L, D), 64x64 tiles, fully vectorized.
// ---------------------------------------------------------------------------
__global__ __launch_bounds__(256) void transpose_dl(const bf16* __restrict__ src,
                                                    bf16* __restrict__ dst) {
    __shared__ bf16 ts[64 * 64];
    const int b = blockIdx.z;
    const int l0 = blockIdx.x * 64, d0 = blockIdx.y * 64;
    const int tid = threadIdx.x;
    {
        const int r0 = tid >> 3, c8 = tid & 7;
#pragma unroll
        for (int h = 0; h < 2; h++) {
            const int r = r0 + h * 32;
            bf16x8 v = *(const bf16x8*)&src[((size_t)b * DD + d0 + r) * LL + l0 + c8 * 8];
            *(bf16x8*)&ts[r * 64 + ((c8 ^ (r & 7)) << 3)] = v;
        }
    }
    __syncthreads();
    const int l = tid & 63, dc0 = (tid >> 6) << 3;
#pragma unroll
    for (int half = 0; half < 2; half++) {
        const int dc = dc0 + half * 32;
        bf16x8 o;
#pragma unroll
        for (int j = 0; j < 8; j++) {
            const int r = dc + j;
            o[j] = ts[r * 64 + (((l >> 3) ^ (r & 7)) << 3) + (l & 7)];
        }
        *(bf16x8*)&dst[((size_t)b * LL + l0 + l) * DD + d0 + dc] = o;
    }
}

// ---------------------------------------------------------------------------
// launch
// ---------------------------------------------------------------------------
extern "C" void kernel_launch(void* const* d_in, const int* in_sizes, int n_in,
                              void* d_out, int out_size, void* d_ws, size_t ws_size,
                              hipStream_t stream) {
    const float* u   = (const float*)d_in[0];
    const float* Wq  = (const float*)d_in[1];
    const float* bq  = (const float*)d_in[2];
    const float* Wk  = (const float*)d_in[3];
    const float* bk  = (const float*)d_in[4];
    const float* Wv  = (const float*)d_in[5];
    const float* bv  = (const float*)d_in[6];
    const float* cqw = (const float*)d_in[7];
    const float* cqb = (const float*)d_in[8];
    const float* ckw = (const float*)d_in[9];
    const float* ckb = (const float*)d_in[10];
    const float* ssm = (const float*)d_in[11];
    const float* Dsk = (const float*)d_in[12];
    const float* Wo  = (const float*)d_in[13];
    const float* bo  = (const float*)d_in[14];

    char* w = (char*)d_ws;
    bf16* u_bf    = (bf16*)(w);                  // 33.55 MB (reused as ygT)
    bf16* Wqkv_bf = (bf16*)(w + 33554432ull);    // 25.2 MB (q|k|v rows concat)
    bf16* Wo_bf   = (bf16*)(w + 58720256ull);    // 8.39 MB
    bf16* qkvT    = (bf16*)(w + 67108864ull);    // 100.7 MB (6144 x 8192)
    bf16* qcT     = (bf16*)(w + 167772160ull);   // 33.55 MB
    bf16* kvT     = (bf16*)(w + 201326592ull);   // 33.55 MB
    // total: 234,881,024 B

    // fused fp32 -> bf16 conversions (u, Wq|Wk|Wv, Wo) in one launch
    cvt_all<<<16384, 256, 0, stream>>>(u, Wq, Wk, Wv, Wo, u_bf, Wqkv_bf, Wo_bf);

    // fused q/k/v projection -> transposed output (E, B*L); 768 wg, 8 waves
    gemm_qkv<<<(MM / 256) * (NN / 256), 512, 0, stream>>>(u_bf, Wqkv_bf, bq, bk, bv, qkvT);

    // depthwise convs + kv (row-wise on transposed layout)
    dwconv_kv2<<<BB * DD, 256, 0, stream>>>(qkvT, cqw, cqb, ckw, ckb, qcT, kvT);

    // causal long conv (Toeplitz MFMA) + gating
    bf16* ygT = u_bf; // reuse
    longconv_gate<<<DD, 128, 0, stream>>>(kvT, qcT, ssm, Dsk, ygT);

    // transpose back to (B,L,E)
    bf16* ygTT = qkvT; // reuse
    dim3 gc(LL / 64, DD / 64, BB);
    transpose_dl<<<gc, 256, 0, stream>>>(ygT, ygTT);

    // output projection -> fp32 d_out; 256 wg, 8 waves
    gemm_bt_f32<<<(MM / 256) * (DD / 256), 512, 0, stream>>>(ygTT, Wo_bf, bo,
                                                             (float*)d_out, DD, DD);
}

// Round 9
// 561.567 us; speedup vs baseline: 1.0575x; 1.0575x over previous
//
#include <hip/hip_runtime.h>
#include <cstdint>
#include <cstddef>

#define DD 2048
#define LL 2048
#define BB 4
#define MM (BB * LL) // 8192
#define NN 6144      // fused q|k|v output columns

typedef __bf16 bf16;
typedef __bf16 bf16x8 __attribute__((ext_vector_type(8)));
typedef __bf16 bf16x4 __attribute__((ext_vector_type(4)));
typedef __bf16 bf16x2 __attribute__((ext_vector_type(2)));
typedef float f32x4 __attribute__((ext_vector_type(4)));

// ---------------------------------------------------------------------------
// async global -> LDS, 16B per lane (wave-uniform base + lane*16 layout)
// ---------------------------------------------------------------------------
__device__ __forceinline__ void gload16(const void* g, void* l) {
    __builtin_amdgcn_global_load_lds(
        (const __attribute__((address_space(1))) void*)g,
        (__attribute__((address_space(3))) void*)l, 16, 0, 0);
}

// ---------------------------------------------------------------------------
// fused fp32 -> bf16 conversion for all 5 tensors (1 launch).
// ---------------------------------------------------------------------------
__global__ __launch_bounds__(256) void cvt_all(
    const float* __restrict__ u, const float* __restrict__ wq,
    const float* __restrict__ wk, const float* __restrict__ wv,
    const float* __restrict__ wo, bf16* __restrict__ u_bf,
    bf16* __restrict__ wqkv, bf16* __restrict__ wo_bf) {
    const int blk = blockIdx.x;
    const float* s;
    bf16* d;
    int base;
    if (blk < 8192)       { s = u;  d = u_bf;            base = 0; }
    else if (blk < 10240) { s = wq; d = wqkv;            base = 8192; }
    else if (blk < 12288) { s = wk; d = wqkv + 4194304;  base = 10240; }
    else if (blk < 14336) { s = wv; d = wqkv + 8388608;  base = 12288; }
    else                  { s = wo; d = wo_bf;           base = 14336; }
    const int i = (blk - base) * 256 + threadIdx.x;
    const float4* sp = (const float4*)s + (size_t)i * 2;
    float4 a = sp[0], b = sp[1];
    bf16x8 o;
    o[0] = (bf16)a.x; o[1] = (bf16)a.y; o[2] = (bf16)a.z; o[3] = (bf16)a.w;
    o[4] = (bf16)b.x; o[5] = (bf16)b.y; o[6] = (bf16)b.z; o[7] = (bf16)b.w;
    *((bf16x8*)d + i) = o;
}

// ---------------------------------------------------------------------------
// 256x256 8-wave K-loop (BK=64, 2 LDS buffers = 128 KiB), within-tile
// register read-ahead, counted vmcnt(4), 2 barriers/K-tile.  (unchanged R4)
// ---------------------------------------------------------------------------
__device__ __forceinline__ void stage_half(const bf16* g, bf16* l, size_t rstep, int tid) {
    gload16(g, l + tid * 8);
    gload16(g + rstep, l + 4096 + tid * 8);
}

#define MFMA_BLK(AF, BQ, IOFF)                                                  \
    __builtin_amdgcn_s_setprio(1);                                              \
    _Pragma("unroll") for (int j = 0; j < 4; j++)                               \
        _Pragma("unroll") for (int i = 0; i < 4; i++)                           \
            acc[(IOFF) + i][j] = __builtin_amdgcn_mfma_f32_16x16x32_bf16(       \
                AF[i], BQ[j], acc[(IOFF) + i][j], 0, 0, 0);                     \
    __builtin_amdgcn_s_setprio(0);

template <int NT>
__device__ __forceinline__ void mma256_loop(const bf16* gA, const bf16* gB,
                                            int Kdim, bf16* lds,
                                            f32x4 (&acc)[8][4]) {
    const int tid = threadIdx.x;
    const int wave = tid >> 6, lane = tid & 63;
    const int wm = wave >> 2, wn = wave & 3;     // 2 x 4 wave grid
    const int fm = lane & 15, fg = lane >> 4;
    const size_t rstep = (size_t)128 * Kdim;
    const int koff = ((fg ^ ((fm >> 1) & 3)) << 3);
    const int aoff = (wm * 128 + fm) * 32 + koff;
    const int boff = (wn * 64 + fm) * 32 + koff;

    bf16* const A0 = lds;
    bf16* const B0 = lds + 32768;

#pragma unroll
    for (int i = 0; i < 8; i++)
#pragma unroll
        for (int j = 0; j < 4; j++) acc[i][j] = (f32x4){0.f, 0.f, 0.f, 0.f};

    stage_half(gA, A0, rstep, tid);
    stage_half(gB, B0, rstep, tid);
    stage_half(gA + 32, A0 + 8192, rstep, tid);
    stage_half(gB + 32, B0 + 8192, rstep, tid);

    bf16x8 af0[4], af1[4], bq0[4], bq1[4];

    for (int t = 0; t < NT; ++t) {
        const int c = t & 1;
        bf16* const Ac = A0 + c * 16384;
        bf16* const Bc = B0 + c * 16384;
        bf16* const An = A0 + (c ^ 1) * 16384;
        bf16* const Bn = B0 + (c ^ 1) * 16384;
        const bf16* a1 = gA + (t + 1) * 64;
        const bf16* b1 = gB + (t + 1) * 64;
        const bool st = (t + 1 < NT);

        // ---- h0 residency gate ----
        asm volatile("s_waitcnt vmcnt(4)" ::: "memory");
        asm volatile("s_barrier" ::: "memory");
#pragma unroll
        for (int i = 0; i < 4; i++) af0[i] = *(const bf16x8*)(Ac + aoff + i * 512);
#pragma unroll
        for (int j = 0; j < 4; j++) bq0[j] = *(const bf16x8*)(Bc + boff + j * 512);
        if (st) stage_half(a1, An, rstep, tid);
#pragma unroll
        for (int i = 0; i < 4; i++) af1[i] = *(const bf16x8*)(Ac + aoff + (i + 4) * 512);
        MFMA_BLK(af0, bq0, 0)
        if (st) stage_half(b1, Bn, rstep, tid);

        // ---- h1 residency gate ----
        if (st) { asm volatile("s_waitcnt vmcnt(4)" ::: "memory"); }
        else    { asm volatile("s_waitcnt vmcnt(0)" ::: "memory"); }
        asm volatile("s_barrier" ::: "memory");
#pragma unroll
        for (int i = 0; i < 4; i++) af0[i] = *(const bf16x8*)(Ac + 8192 + aoff + i * 512);
#pragma unroll
        for (int j = 0; j < 4; j++) bq1[j] = *(const bf16x8*)(Bc + 8192 + boff + j * 512);
        if (st) stage_half(a1 + 32, An + 8192, rstep, tid);
        MFMA_BLK(af1, bq0, 4)
#pragma unroll
        for (int i = 0; i < 4; i++) af1[i] = *(const bf16x8*)(Ac + 8192 + aoff + (i + 4) * 512);
        if (st) stage_half(b1 + 32, Bn + 8192, rstep, tid);
        MFMA_BLK(af0, bq1, 0)
        MFMA_BLK(af1, bq1, 4)
    }
}

// ---------------------------------------------------------------------------
// Fused QKV GEMM -> transposed bf16 output (6144, 8192).  (unchanged)
// ---------------------------------------------------------------------------
__global__ __launch_bounds__(512, 2) void gemm_qkv(const bf16* __restrict__ A,
                                                   const bf16* __restrict__ Bm,
                                                   const float* __restrict__ bqp,
                                                   const float* __restrict__ bkp,
                                                   const float* __restrict__ bvp,
                                                   bf16* __restrict__ CtOut) {
    __shared__ bf16 lds[65536];
    const int id = blockIdx.x;        // nwg = 768 = 8 XCD x (4m x 24n)
    const int xcd = id & 7, li = id >> 3;
    const int m0 = (xcd * 4 + (li & 3)) << 8;
    const int n0 = (li >> 2) << 8;

    const int tid = threadIdx.x;
    const int wave = tid >> 6, lane = tid & 63;
    const int srow = tid >> 2;
    const int skx = (((lane & 3) ^ ((lane >> 3) & 3)) << 3);
    const bf16* gA = A + (size_t)(m0 + srow) * DD + skx;
    const bf16* gB = Bm + (size_t)(n0 + srow) * DD + skx;

    f32x4 acc[8][4];
    mma256_loop<DD / 64>(gA, gB, DD, lds, acc);

    __syncthreads();
    const int wm = wave >> 2, wn = wave & 3;
    const int fm = lane & 15, fg = lane >> 4;
    const float* bp = (n0 < 2048) ? bqp : ((n0 < 4096) ? bkp : bvp);
    const int nb = n0 & 2047;
#pragma unroll
    for (int j = 0; j < 4; j++) {
        const int col = wn * 64 + j * 16 + fm;
        const float bvv = bp[nb + col];
        const int csw = (col & 7) << 3;
#pragma unroll
        for (int i = 0; i < 8; i++) {
            const int row = (wm * 128 + i * 16 + fg * 4) ^ csw;
            bf16x4 o;
#pragma unroll
            for (int r = 0; r < 4; r++) o[r] = (bf16)(acc[i][j][r] + bvv);
            *(bf16x4*)&lds[col * 256 + row] = o;
        }
    }
    __syncthreads();
    const int ccol = tid >> 5, chunk = tid & 31;
#pragma unroll
    for (int p = 0; p < 16; p++) {
        const int col = p * 16 + ccol;
        bf16x8 vv = *(const bf16x8*)&lds[col * 256 + ((chunk * 8) ^ ((col & 7) << 3))];
        *(bf16x8*)(CtOut + (size_t)(n0 + col) * MM + m0 + chunk * 8) = vv;
    }
}

// ---------------------------------------------------------------------------
// Output projection GEMM (row-major f32 out).  (unchanged)
// ---------------------------------------------------------------------------
__global__ __launch_bounds__(512, 2) void gemm_bt_f32(const bf16* __restrict__ A,
                                                      const bf16* __restrict__ Bm,
                                                      const float* __restrict__ bias,
                                                      float* __restrict__ C,
                                                      int Ndim, int Kdim) {
    __shared__ bf16 lds[65536];
    const int id = blockIdx.x;
    const int xcd = id & 7, li = id >> 3;
    const int m0 = (xcd * 4 + (li & 3)) << 8;
    const int n0 = (li >> 2) << 8;

    const int tid = threadIdx.x;
    const int wave = tid >> 6, lane = tid & 63;
    const int srow = tid >> 2;
    const int skx = (((lane & 3) ^ ((lane >> 3) & 3)) << 3);
    const bf16* gA = A + (size_t)(m0 + srow) * Kdim + skx;
    const bf16* gB = Bm + (size_t)(n0 + srow) * Kdim + skx;

    f32x4 acc[8][4];
    mma256_loop<DD / 64>(gA, gB, Kdim, lds, acc);

    const int wm = wave >> 2, wn = wave & 3;
    const int fm = lane & 15, fg = lane >> 4;
#pragma unroll
    for (int j = 0; j < 4; j++) {
        const int col = n0 + wn * 64 + j * 16 + fm;
        const float bvv = bias[col];
#pragma unroll
        for (int i = 0; i < 8; i++) {
#pragma unroll
            for (int r = 0; r < 4; r++) {
                const int row = m0 + wm * 128 + i * 16 + fg * 4 + r;
                C[(size_t)row * Ndim + col] = acc[i][j][r] + bvv;
            }
        }
    }
}

// ---------------------------------------------------------------------------
// FUSED depthwise conv + causal long conv + D-skip + q gating (R7).
// One block per d.  Phase 1 computes width-3 causal convs for all 4 batches
// DIRECTLY INTO LDS (kv_ls, qc_ls) -- removes the qcT/kvT HBM round trip
// (67 MB write + 67 MB read) and the separate dwconv launch.  Phase 2 is the
// R4-exact Toeplitz-MFMA loop (stride 2112, scalar krev_f window reads).
// LDS: kv 16.9K + qc 16.9K + krev 8.4K = 42.2 KB -> 3 blocks/CU.
// ---------------------------------------------------------------------------
#define KVS 2112
__global__ __launch_bounds__(128, 2) void dwlc_gate(
    const bf16* __restrict__ qkvT,
    const float* __restrict__ cqw, const float* __restrict__ cqb,
    const float* __restrict__ ckw, const float* __restrict__ ckb,
    const float* __restrict__ kern, const float* __restrict__ Dskip,
    bf16* __restrict__ ygT) {
    __shared__ bf16 kv_ls[4 * KVS];
    __shared__ bf16 qc_ls[4 * KVS];
    __shared__ float krev_f[2112];
    const int d = blockIdx.x;
    const int tid = threadIdx.x;

    // ---- zero the Toeplitz pad regions ----
    if (tid < 48) {
#pragma unroll
        for (int b2 = 0; b2 < 4; b2++) kv_ls[KVS * b2 + tid] = (bf16)0.f;
    } else if (tid < 64) {
#pragma unroll
        for (int b2 = 0; b2 < 4; b2++) kv_ls[KVS * b2 + 2048 + tid] = (bf16)0.f;
    }

    // ---- reversed kernel (f32) ----
    {
        const float* kr = kern + (size_t)d * LL;
#pragma unroll
        for (int c = 0; c < 16; ++c) {
            const int x = c * 128 + tid;
            krev_f[x] = kr[2047 - x];
        }
        if (tid < 64) krev_f[2048 + tid] = 0.f;
    }

    // ---- depthwise convs for all 4 batches -> LDS (16 l per thread per b) ----
    {
        const float q0 = cqw[d * 3], q1 = cqw[d * 3 + 1], q2 = cqw[d * 3 + 2];
        const float k0 = ckw[d * 3], k1 = ckw[d * 3 + 1], k2 = ckw[d * 3 + 2];
        const float qb = cqb[d], kb = ckb[d];
#pragma unroll
        for (int b = 0; b < 4; ++b) {
            const bf16* qR = qkvT + (size_t)d * MM + b * LL;
            const bf16* kR = qkvT + (size_t)(2048 + d) * MM + b * LL;
            const bf16* vR = qkvT + (size_t)(4096 + d) * MM + b * LL;
#pragma unroll
            for (int h = 0; h < 2; ++h) {
                const int l = tid * 16 + h * 8;
                bf16x8 qx = *(const bf16x8*)(qR + l);
                bf16x8 kx = *(const bf16x8*)(kR + l);
                bf16x8 vx = *(const bf16x8*)(vR + l);
                float xq[10], xk[10];
                xq[0] = 0.f; xq[1] = 0.f; xk[0] = 0.f; xk[1] = 0.f;
                if (l >= 2) {
                    bf16x2 qh = *(const bf16x2*)(qR + l - 2);
                    bf16x2 kh = *(const bf16x2*)(kR + l - 2);
                    xq[0] = (float)qh[0]; xq[1] = (float)qh[1];
                    xk[0] = (float)kh[0]; xk[1] = (float)kh[1];
                }
#pragma unroll
                for (int c = 0; c < 8; c++) {
                    xq[c + 2] = (float)qx[c];
                    xk[c + 2] = (float)kx[c];
                }
                bf16x8 oq, okv;
#pragma unroll
                for (int c = 0; c < 8; c++) {
                    float qc = q0 * xq[c] + q1 * xq[c + 1] + q2 * xq[c + 2] + qb;
                    float kc = k0 * xk[c] + k1 * xk[c + 1] + k2 * xk[c + 2] + kb;
                    oq[c] = (bf16)qc;
                    okv[c] = (bf16)(kc * (float)vx[c]);
                }
                *(bf16x8*)&kv_ls[KVS * b + 48 + l] = okv;
                *(bf16x8*)&qc_ls[KVS * b + l] = oq;
            }
        }
    }
    __syncthreads();

    // ---- R4-exact Toeplitz MFMA main loop ----
    const int lane = tid & 63;
    const int w = __builtin_amdgcn_readfirstlane(tid >> 6);
    const int n = lane & 15, q = lane >> 4;
    const int b = n & 3, pp = n >> 2;
    const int cB = KVS * b + 16 * pp + 8 * q;

    f32x4 acc[16];
#pragma unroll
    for (int s = 0; s < 16; s++) acc[s] = (f32x4){0.f, 0.f, 0.f, 0.f};

    for (int it = 0; it < 64; ++it) {
        const int as = 2031 - 32 * it - n + 8 * q;
        float af[8];
#pragma unroll
        for (int j = 0; j < 8; j++) af[j] = krev_f[as + j];
        bf16x8 a;
#pragma unroll
        for (int j = 0; j < 8; j++) a[j] = (bf16)af[j];

        const int bbase = cB + 64 * w + 32 - 32 * it;
#pragma unroll
        for (int h = 0; h < 2; ++h) {
            bf16x8 bfr[8];
#pragma unroll
            for (int s8 = 0; s8 < 8; s8++) {
                const int s = h * 8 + s8;
                if (it <= 4 * s + 2 * w + 1)
                    bfr[s8] = *(const bf16x8*)&kv_ls[bbase + 128 * s];
            }
#pragma unroll
            for (int s8 = 0; s8 < 8; s8++) {
                const int s = h * 8 + s8;
                if (it <= 4 * s + 2 * w + 1)
                    acc[s] = __builtin_amdgcn_mfma_f32_16x16x32_bf16(
                        a, bfr[s8], acc[s], 0, 0, 0);
            }
        }
    }

    // ---- epilogue: D-skip + q gating, qc/kv from LDS ----
    const float dsk = Dskip[d];
#pragma unroll
    for (int s = 0; s < 16; s++) {
        const int i = 2 * s + w;
        const int l = 64 * i + 16 * pp + 4 * q;
        const size_t gb = ((size_t)b * DD + d) * LL + l;
        bf16x4 qc4 = *(const bf16x4*)&qc_ls[KVS * b + l];
        bf16x4 kv4 = *(const bf16x4*)&kv_ls[KVS * b + 48 + l];
        bf16x4 o;
#pragma unroll
        for (int r = 0; r < 4; r++) {
            float val = (acc[s][r] + (float)kv4[r] * dsk) * (float)qc4[r];
            o[r] = (bf16)val;
        }
        *(bf16x4*)&ygT[gb] = o;
    }
}

// ---------------------------------------------------------------------------
// bf16 transpose (B, D, L) -> (B, L, D), 64x64 tiles, fully vectorized.
// ---------------------------------------------------------------------------
__global__ __launch_bounds__(256) void transpose_dl(const bf16* __restrict__ src,
                                                    bf16* __restrict__ dst) {
    __shared__ bf16 ts[64 * 64];
    const int b = blockIdx.z;
    const int l0 = blockIdx.x * 64, d0 = blockIdx.y * 64;
    const int tid = threadIdx.x;
    {
        const int r0 = tid >> 3, c8 = tid & 7;
#pragma unroll
        for (int h = 0; h < 2; h++) {
            const int r = r0 + h * 32;
            bf16x8 v = *(const bf16x8*)&src[((size_t)b * DD + d0 + r) * LL + l0 + c8 * 8];
            *(bf16x8*)&ts[r * 64 + ((c8 ^ (r & 7)) << 3)] = v;
        }
    }
    __syncthreads();
    const int l = tid & 63, dc0 = (tid >> 6) << 3;
#pragma unroll
    for (int half = 0; half < 2; half++) {
        const int dc = dc0 + half * 32;
        bf16x8 o;
#pragma unroll
        for (int j = 0; j < 8; j++) {
            const int r = dc + j;
            o[j] = ts[r * 64 + (((l >> 3) ^ (r & 7)) << 3) + (l & 7)];
        }
        *(bf16x8*)&dst[((size_t)b * LL + l0 + l) * DD + d0 + dc] = o;
    }
}

// ---------------------------------------------------------------------------
// launch
// ---------------------------------------------------------------------------
extern "C" void kernel_launch(void* const* d_in, const int* in_sizes, int n_in,
                              void* d_out, int out_size, void* d_ws, size_t ws_size,
                              hipStream_t stream) {
    const float* u   = (const float*)d_in[0];
    const float* Wq  = (const float*)d_in[1];
    const float* bq  = (const float*)d_in[2];
    const float* Wk  = (const float*)d_in[3];
    const float* bk  = (const float*)d_in[4];
    const float* Wv  = (const float*)d_in[5];
    const float* bv  = (const float*)d_in[6];
    const float* cqw = (const float*)d_in[7];
    const float* cqb = (const float*)d_in[8];
    const float* ckw = (const float*)d_in[9];
    const float* ckb = (const float*)d_in[10];
    const float* ssm = (const float*)d_in[11];
    const float* Dsk = (const float*)d_in[12];
    const float* Wo  = (const float*)d_in[13];
    const float* bo  = (const float*)d_in[14];

    char* w = (char*)d_ws;
    bf16* u_bf    = (bf16*)(w);                  // 33.55 MB (reused as ygT)
    bf16* Wqkv_bf = (bf16*)(w + 33554432ull);    // 25.2 MB (q|k|v rows concat)
    bf16* Wo_bf   = (bf16*)(w + 58720256ull);    // 8.39 MB
    bf16* qkvT    = (bf16*)(w + 67108864ull);    // 100.7 MB (6144 x 8192)
    // (qcT/kvT buffers no longer needed -- dwconv fused into dwlc_gate)

    // fused fp32 -> bf16 conversions (u, Wq|Wk|Wv, Wo) in one launch
    cvt_all<<<16384, 256, 0, stream>>>(u, Wq, Wk, Wv, Wo, u_bf, Wqkv_bf, Wo_bf);

    // fused q/k/v projection -> transposed output (E, B*L); 768 wg, 8 waves
    gemm_qkv<<<(MM / 256) * (NN / 256), 512, 0, stream>>>(u_bf, Wqkv_bf, bq, bk, bv, qkvT);

    // fused depthwise convs + causal long conv (Toeplitz MFMA) + gating
    bf16* ygT = u_bf; // reuse
    dwlc_gate<<<DD, 128, 0, stream>>>(qkvT, cqw, cqb, ckw, ckb, ssm, Dsk, ygT);

    // transpose back to (B,L,E)
    bf16* ygTT = qkvT; // reuse
    dim3 gc(LL / 64, DD / 64, BB);
    transpose_dl<<<gc, 256, 0, stream>>>(ygT, ygTT);

    // output projection -> fp32 d_out; 256 wg, 8 waves
    gemm_bt_f32<<<(MM / 256) * (DD / 256), 512, 0, stream>>>(ygTT, Wo_bf, bo,
                                                             (float*)d_out, DD, DD);
}

// Round 10
// 556.999 us; speedup vs baseline: 1.0662x; 1.0082x over previous
//
#include <hip/hip_runtime.h>
#include <cstdint>
#include <cstddef>

#define DD 2048
#define LL 2048
#define BB 4
#define MM (BB * LL) // 8192
#define NN 6144      // fused q|k|v output columns

typedef __bf16 bf16;
typedef __bf16 bf16x8 __attribute__((ext_vector_type(8)));
typedef __bf16 bf16x4 __attribute__((ext_vector_type(4)));
typedef __bf16 bf16x2 __attribute__((ext_vector_type(2)));
typedef float f32x4 __attribute__((ext_vector_type(4)));

// ---------------------------------------------------------------------------
// async global -> LDS, 16B per lane (wave-uniform base + lane*16 layout)
// ---------------------------------------------------------------------------
__device__ __forceinline__ void gload16(const void* g, void* l) {
    __builtin_amdgcn_global_load_lds(
        (const __attribute__((address_space(1))) void*)g,
        (__attribute__((address_space(3))) void*)l, 16, 0, 0);
}

// ---------------------------------------------------------------------------
// fused fp32 -> bf16 conversion for all 5 tensors (1 launch).
// ---------------------------------------------------------------------------
__global__ __launch_bounds__(256) void cvt_all(
    const float* __restrict__ u, const float* __restrict__ wq,
    const float* __restrict__ wk, const float* __restrict__ wv,
    const float* __restrict__ wo, bf16* __restrict__ u_bf,
    bf16* __restrict__ wqkv, bf16* __restrict__ wo_bf) {
    const int blk = blockIdx.x;
    const float* s;
    bf16* d;
    int base;
    if (blk < 8192)       { s = u;  d = u_bf;            base = 0; }
    else if (blk < 10240) { s = wq; d = wqkv;            base = 8192; }
    else if (blk < 12288) { s = wk; d = wqkv + 4194304;  base = 10240; }
    else if (blk < 14336) { s = wv; d = wqkv + 8388608;  base = 12288; }
    else                  { s = wo; d = wo_bf;           base = 14336; }
    const int i = (blk - base) * 256 + threadIdx.x;
    const float4* sp = (const float4*)s + (size_t)i * 2;
    float4 a = sp[0], b = sp[1];
    bf16x8 o;
    o[0] = (bf16)a.x; o[1] = (bf16)a.y; o[2] = (bf16)a.z; o[3] = (bf16)a.w;
    o[4] = (bf16)b.x; o[5] = (bf16)b.y; o[6] = (bf16)b.z; o[7] = (bf16)b.w;
    *((bf16x8*)d + i) = o;
}

// ---------------------------------------------------------------------------
// 256x256 8-wave K-loop (BK=64, 2 LDS buffers = 128 KiB), within-tile
// register read-ahead, counted vmcnt(4), 2 barriers/K-tile.  (unchanged R4)
// ---------------------------------------------------------------------------
__device__ __forceinline__ void stage_half(const bf16* g, bf16* l, size_t rstep, int tid) {
    gload16(g, l + tid * 8);
    gload16(g + rstep, l + 4096 + tid * 8);
}

#define MFMA_BLK(AF, BQ, IOFF)                                                  \
    __builtin_amdgcn_s_setprio(1);                                              \
    _Pragma("unroll") for (int j = 0; j < 4; j++)                               \
        _Pragma("unroll") for (int i = 0; i < 4; i++)                           \
            acc[(IOFF) + i][j] = __builtin_amdgcn_mfma_f32_16x16x32_bf16(       \
                AF[i], BQ[j], acc[(IOFF) + i][j], 0, 0, 0);                     \
    __builtin_amdgcn_s_setprio(0);

template <int NT>
__device__ __forceinline__ void mma256_loop(const bf16* gA, const bf16* gB,
                                            int Kdim, bf16* lds,
                                            f32x4 (&acc)[8][4]) {
    const int tid = threadIdx.x;
    const int wave = tid >> 6, lane = tid & 63;
    const int wm = wave >> 2, wn = wave & 3;     // 2 x 4 wave grid
    const int fm = lane & 15, fg = lane >> 4;
    const size_t rstep = (size_t)128 * Kdim;
    const int koff = ((fg ^ ((fm >> 1) & 3)) << 3);
    const int aoff = (wm * 128 + fm) * 32 + koff;
    const int boff = (wn * 64 + fm) * 32 + koff;

    bf16* const A0 = lds;
    bf16* const B0 = lds + 32768;

#pragma unroll
    for (int i = 0; i < 8; i++)
#pragma unroll
        for (int j = 0; j < 4; j++) acc[i][j] = (f32x4){0.f, 0.f, 0.f, 0.f};

    stage_half(gA, A0, rstep, tid);
    stage_half(gB, B0, rstep, tid);
    stage_half(gA + 32, A0 + 8192, rstep, tid);
    stage_half(gB + 32, B0 + 8192, rstep, tid);

    bf16x8 af0[4], af1[4], bq0[4], bq1[4];

    for (int t = 0; t < NT; ++t) {
        const int c = t & 1;
        bf16* const Ac = A0 + c * 16384;
        bf16* const Bc = B0 + c * 16384;
        bf16* const An = A0 + (c ^ 1) * 16384;
        bf16* const Bn = B0 + (c ^ 1) * 16384;
        const bf16* a1 = gA + (t + 1) * 64;
        const bf16* b1 = gB + (t + 1) * 64;
        const bool st = (t + 1 < NT);

        // ---- h0 residency gate ----
        asm volatile("s_waitcnt vmcnt(4)" ::: "memory");
        asm volatile("s_barrier" ::: "memory");
#pragma unroll
        for (int i = 0; i < 4; i++) af0[i] = *(const bf16x8*)(Ac + aoff + i * 512);
#pragma unroll
        for (int j = 0; j < 4; j++) bq0[j] = *(const bf16x8*)(Bc + boff + j * 512);
        if (st) stage_half(a1, An, rstep, tid);
#pragma unroll
        for (int i = 0; i < 4; i++) af1[i] = *(const bf16x8*)(Ac + aoff + (i + 4) * 512);
        MFMA_BLK(af0, bq0, 0)
        if (st) stage_half(b1, Bn, rstep, tid);

        // ---- h1 residency gate ----
        if (st) { asm volatile("s_waitcnt vmcnt(4)" ::: "memory"); }
        else    { asm volatile("s_waitcnt vmcnt(0)" ::: "memory"); }
        asm volatile("s_barrier" ::: "memory");
#pragma unroll
        for (int i = 0; i < 4; i++) af0[i] = *(const bf16x8*)(Ac + 8192 + aoff + i * 512);
#pragma unroll
        for (int j = 0; j < 4; j++) bq1[j] = *(const bf16x8*)(Bc + 8192 + boff + j * 512);
        if (st) stage_half(a1 + 32, An + 8192, rstep, tid);
        MFMA_BLK(af1, bq0, 4)
#pragma unroll
        for (int i = 0; i < 4; i++) af1[i] = *(const bf16x8*)(Ac + 8192 + aoff + (i + 4) * 512);
        if (st) stage_half(b1 + 32, Bn + 8192, rstep, tid);
        MFMA_BLK(af0, bq1, 0)
        MFMA_BLK(af1, bq1, 4)
    }
}

// ---------------------------------------------------------------------------
// Fused QKV GEMM -> transposed bf16 output (6144, 8192).  (unchanged)
// ---------------------------------------------------------------------------
__global__ __launch_bounds__(512, 2) void gemm_qkv(const bf16* __restrict__ A,
                                                   const bf16* __restrict__ Bm,
                                                   const float* __restrict__ bqp,
                                                   const float* __restrict__ bkp,
                                                   const float* __restrict__ bvp,
                                                   bf16* __restrict__ CtOut) {
    __shared__ bf16 lds[65536];
    const int id = blockIdx.x;        // nwg = 768 = 8 XCD x (4m x 24n)
    const int xcd = id & 7, li = id >> 3;
    const int m0 = (xcd * 4 + (li & 3)) << 8;
    const int n0 = (li >> 2) << 8;

    const int tid = threadIdx.x;
    const int wave = tid >> 6, lane = tid & 63;
    const int srow = tid >> 2;
    const int skx = (((lane & 3) ^ ((lane >> 3) & 3)) << 3);
    const bf16* gA = A + (size_t)(m0 + srow) * DD + skx;
    const bf16* gB = Bm + (size_t)(n0 + srow) * DD + skx;

    f32x4 acc[8][4];
    mma256_loop<DD / 64>(gA, gB, DD, lds, acc);

    __syncthreads();
    const int wm = wave >> 2, wn = wave & 3;
    const int fm = lane & 15, fg = lane >> 4;
    const float* bp = (n0 < 2048) ? bqp : ((n0 < 4096) ? bkp : bvp);
    const int nb = n0 & 2047;
#pragma unroll
    for (int j = 0; j < 4; j++) {
        const int col = wn * 64 + j * 16 + fm;
        const float bvv = bp[nb + col];
        const int csw = (col & 7) << 3;
#pragma unroll
        for (int i = 0; i < 8; i++) {
            const int row = (wm * 128 + i * 16 + fg * 4) ^ csw;
            bf16x4 o;
#pragma unroll
            for (int r = 0; r < 4; r++) o[r] = (bf16)(acc[i][j][r] + bvv);
            *(bf16x4*)&lds[col * 256 + row] = o;
        }
    }
    __syncthreads();
    const int ccol = tid >> 5, chunk = tid & 31;
#pragma unroll
    for (int p = 0; p < 16; p++) {
        const int col = p * 16 + ccol;
        bf16x8 vv = *(const bf16x8*)&lds[col * 256 + ((chunk * 8) ^ ((col & 7) << 3))];
        *(bf16x8*)(CtOut + (size_t)(n0 + col) * MM + m0 + chunk * 8) = vv;
    }
}

// ---------------------------------------------------------------------------
// Output projection GEMM (row-major f32 out).  (unchanged)
// ---------------------------------------------------------------------------
__global__ __launch_bounds__(512, 2) void gemm_bt_f32(const bf16* __restrict__ A,
                                                      const bf16* __restrict__ Bm,
                                                      const float* __restrict__ bias,
                                                      float* __restrict__ C,
                                                      int Ndim, int Kdim) {
    __shared__ bf16 lds[65536];
    const int id = blockIdx.x;
    const int xcd = id & 7, li = id >> 3;
    const int m0 = (xcd * 4 + (li & 3)) << 8;
    const int n0 = (li >> 2) << 8;

    const int tid = threadIdx.x;
    const int wave = tid >> 6, lane = tid & 63;
    const int srow = tid >> 2;
    const int skx = (((lane & 3) ^ ((lane >> 3) & 3)) << 3);
    const bf16* gA = A + (size_t)(m0 + srow) * Kdim + skx;
    const bf16* gB = Bm + (size_t)(n0 + srow) * Kdim + skx;

    f32x4 acc[8][4];
    mma256_loop<DD / 64>(gA, gB, Kdim, lds, acc);

    const int wm = wave >> 2, wn = wave & 3;
    const int fm = lane & 15, fg = lane >> 4;
#pragma unroll
    for (int j = 0; j < 4; j++) {
        const int col = n0 + wn * 64 + j * 16 + fm;
        const float bvv = bias[col];
#pragma unroll
        for (int i = 0; i < 8; i++) {
#pragma unroll
            for (int r = 0; r < 4; r++) {
                const int row = m0 + wm * 128 + i * 16 + fg * 4 + r;
                C[(size_t)row * Ndim + col] = acc[i][j][r] + bvv;
            }
        }
    }
}

// ---------------------------------------------------------------------------
// FUSED depthwise conv + causal long conv + D-skip + q gating (R10).
// CHANGE vs R9: qc_ls ELIMINATED.  Phase 1 computes only kv = conv(k)*v into
// LDS; the q-gate conv is recomputed in the epilogue from two 8B global reads
// per output quad (q-plane unique HBM bytes unchanged, just moved).  LDS
// drops 42.2 -> 25.3 KB => 3 -> 6 blocks/CU (6 -> 12 waves/CU), and phase 1
// sheds 1/3 of its global traffic + the q-conv VALU.
// ---------------------------------------------------------------------------
#define KVS 2112
__global__ __launch_bounds__(128, 2) void dwlc_gate(
    const bf16* __restrict__ qkvT,
    const float* __restrict__ cqw, const float* __restrict__ cqb,
    const float* __restrict__ ckw, const float* __restrict__ ckb,
    const float* __restrict__ kern, const float* __restrict__ Dskip,
    bf16* __restrict__ ygT) {
    __shared__ bf16 kv_ls[4 * KVS];
    __shared__ float krev_f[2112];
    const int d = blockIdx.x;
    const int tid = threadIdx.x;

    // ---- zero the Toeplitz pad regions ----
    if (tid < 48) {
#pragma unroll
        for (int b2 = 0; b2 < 4; b2++) kv_ls[KVS * b2 + tid] = (bf16)0.f;
    } else if (tid < 64) {
#pragma unroll
        for (int b2 = 0; b2 < 4; b2++) kv_ls[KVS * b2 + 2048 + tid] = (bf16)0.f;
    }

    // ---- reversed kernel (f32) ----
    {
        const float* kr = kern + (size_t)d * LL;
#pragma unroll
        for (int c = 0; c < 16; ++c) {
            const int x = c * 128 + tid;
            krev_f[x] = kr[2047 - x];
        }
        if (tid < 64) krev_f[2048 + tid] = 0.f;
    }

    // ---- kv conv for all 4 batches -> LDS (k,v only; q handled in epilogue) ----
    {
        const float k0 = ckw[d * 3], k1 = ckw[d * 3 + 1], k2 = ckw[d * 3 + 2];
        const float kb = ckb[d];
#pragma unroll
        for (int b = 0; b < 4; ++b) {
            const bf16* kR = qkvT + (size_t)(2048 + d) * MM + b * LL;
            const bf16* vR = qkvT + (size_t)(4096 + d) * MM + b * LL;
#pragma unroll
            for (int h = 0; h < 2; ++h) {
                const int l = tid * 16 + h * 8;
                bf16x8 kx = *(const bf16x8*)(kR + l);
                bf16x8 vx = *(const bf16x8*)(vR + l);
                float xk[10];
                xk[0] = 0.f; xk[1] = 0.f;
                if (l >= 2) {
                    bf16x2 kh = *(const bf16x2*)(kR + l - 2);
                    xk[0] = (float)kh[0]; xk[1] = (float)kh[1];
                }
#pragma unroll
                for (int c = 0; c < 8; c++) xk[c + 2] = (float)kx[c];
                bf16x8 okv;
#pragma unroll
                for (int c = 0; c < 8; c++) {
                    float kc = k0 * xk[c] + k1 * xk[c + 1] + k2 * xk[c + 2] + kb;
                    okv[c] = (bf16)(kc * (float)vx[c]);
                }
                *(bf16x8*)&kv_ls[KVS * b + 48 + l] = okv;
            }
        }
    }
    __syncthreads();

    // ---- R4-exact Toeplitz MFMA main loop ----
    const int lane = tid & 63;
    const int w = __builtin_amdgcn_readfirstlane(tid >> 6);
    const int n = lane & 15, q = lane >> 4;
    const int b = n & 3, pp = n >> 2;
    const int cB = KVS * b + 16 * pp + 8 * q;

    f32x4 acc[16];
#pragma unroll
    for (int s = 0; s < 16; s++) acc[s] = (f32x4){0.f, 0.f, 0.f, 0.f};

    for (int it = 0; it < 64; ++it) {
        const int as = 2031 - 32 * it - n + 8 * q;
        float af[8];
#pragma unroll
        for (int j = 0; j < 8; j++) af[j] = krev_f[as + j];
        bf16x8 a;
#pragma unroll
        for (int j = 0; j < 8; j++) a[j] = (bf16)af[j];

        const int bbase = cB + 64 * w + 32 - 32 * it;
#pragma unroll
        for (int h = 0; h < 2; ++h) {
            bf16x8 bfr[8];
#pragma unroll
            for (int s8 = 0; s8 < 8; s8++) {
                const int s = h * 8 + s8;
                if (it <= 4 * s + 2 * w + 1)
                    bfr[s8] = *(const bf16x8*)&kv_ls[bbase + 128 * s];
            }
#pragma unroll
            for (int s8 = 0; s8 < 8; s8++) {
                const int s = h * 8 + s8;
                if (it <= 4 * s + 2 * w + 1)
                    acc[s] = __builtin_amdgcn_mfma_f32_16x16x32_bf16(
                        a, bfr[s8], acc[s], 0, 0, 0);
            }
        }
    }

    // ---- epilogue: D-skip + q-gate conv recomputed from global q-plane ----
    const float q0 = cqw[d * 3], q1 = cqw[d * 3 + 1], q2 = cqw[d * 3 + 2];
    const float qb = cqb[d];
    const float dsk = Dskip[d];
    const bf16* qR = qkvT + (size_t)d * MM + b * LL;
#pragma unroll
    for (int s = 0; s < 16; s++) {
        const int i = 2 * s + w;
        const int l = 64 * i + 16 * pp + 4 * q;
        const size_t gb = ((size_t)b * DD + d) * LL + l;
        bf16x4 cx = *(const bf16x4*)&qR[l];
        bf16x4 hx;
        if (l >= 4) hx = *(const bf16x4*)&qR[l - 4];
        else { hx[0] = (bf16)0.f; hx[1] = (bf16)0.f; hx[2] = (bf16)0.f; hx[3] = (bf16)0.f; }
        float x2[6] = { (float)hx[2], (float)hx[3], (float)cx[0],
                        (float)cx[1], (float)cx[2], (float)cx[3] }; // x2[j] = q[l-2+j]
        bf16x4 kv4 = *(const bf16x4*)&kv_ls[KVS * b + 48 + l];
        bf16x4 o;
#pragma unroll
        for (int r = 0; r < 4; r++) {
            const float qc = q0 * x2[r] + q1 * x2[r + 1] + q2 * x2[r + 2] + qb;
            const float val = (acc[s][r] + (float)kv4[r] * dsk) * qc;
            o[r] = (bf16)val;
        }
        *(bf16x4*)&ygT[gb] = o;
    }
}

// ---------------------------------------------------------------------------
// bf16 transpose (B, D, L) -> (B, L, D), 64x64 tiles, fully vectorized.
// ---------------------------------------------------------------------------
__global__ __launch_bounds__(256) void transpose_dl(const bf16* __restrict__ src,
                                                    bf16* __restrict__ dst) {
    __shared__ bf16 ts[64 * 64];
    const int b = blockIdx.z;
    const int l0 = blockIdx.x * 64, d0 = blockIdx.y * 64;
    const int tid = threadIdx.x;
    {
        const int r0 = tid >> 3, c8 = tid & 7;
#pragma unroll
        for (int h = 0; h < 2; h++) {
            const int r = r0 + h * 32;
            bf16x8 v = *(const bf16x8*)&src[((size_t)b * DD + d0 + r) * LL + l0 + c8 * 8];
            *(bf16x8*)&ts[r * 64 + ((c8 ^ (r & 7)) << 3)] = v;
        }
    }
    __syncthreads();
    const int l = tid & 63, dc0 = (tid >> 6) << 3;
#pragma unroll
    for (int half = 0; half < 2; half++) {
        const int dc = dc0 + half * 32;
        bf16x8 o;
#pragma unroll
        for (int j = 0; j < 8; j++) {
            const int r = dc + j;
            o[j] = ts[r * 64 + (((l >> 3) ^ (r & 7)) << 3) + (l & 7)];
        }
        *(bf16x8*)&dst[((size_t)b * LL + l0 + l) * DD + d0 + dc] = o;
    }
}

// ---------------------------------------------------------------------------
// launch
// ---------------------------------------------------------------------------
extern "C" void kernel_launch(void* const* d_in, const int* in_sizes, int n_in,
                              void* d_out, int out_size, void* d_ws, size_t ws_size,
                              hipStream_t stream) {
    const float* u   = (const float*)d_in[0];
    const float* Wq  = (const float*)d_in[1];
    const float* bq  = (const float*)d_in[2];
    const float* Wk  = (const float*)d_in[3];
    const float* bk  = (const float*)d_in[4];
    const float* Wv  = (const float*)d_in[5];
    const float* bv  = (const float*)d_in[6];
    const float* cqw = (const float*)d_in[7];
    const float* cqb = (const float*)d_in[8];
    const float* ckw = (const float*)d_in[9];
    const float* ckb = (const float*)d_in[10];
    const float* ssm = (const float*)d_in[11];
    const float* Dsk = (const float*)d_in[12];
    const float* Wo  = (const float*)d_in[13];
    const float* bo  = (const float*)d_in[14];

    char* w = (char*)d_ws;
    bf16* u_bf    = (bf16*)(w);                  // 33.55 MB (reused as ygT)
    bf16* Wqkv_bf = (bf16*)(w + 33554432ull);    // 25.2 MB (q|k|v rows concat)
    bf16* Wo_bf   = (bf16*)(w + 58720256ull);    // 8.39 MB
    bf16* qkvT    = (bf16*)(w + 67108864ull);    // 100.7 MB (6144 x 8192)

    // fused fp32 -> bf16 conversions (u, Wq|Wk|Wv, Wo) in one launch
    cvt_all<<<16384, 256, 0, stream>>>(u, Wq, Wk, Wv, Wo, u_bf, Wqkv_bf, Wo_bf);

    // fused q/k/v projection -> transposed output (E, B*L); 768 wg, 8 waves
    gemm_qkv<<<(MM / 256) * (NN / 256), 512, 0, stream>>>(u_bf, Wqkv_bf, bq, bk, bv, qkvT);

    // fused depthwise convs + causal long conv (Toeplitz MFMA) + gating
    bf16* ygT = u_bf; // reuse
    dwlc_gate<<<DD, 128, 0, stream>>>(qkvT, cqw, cqb, ckw, ckb, ssm, Dsk, ygT);

    // transpose back to (B,L,E)
    bf16* ygTT = qkvT; // reuse
    dim3 gc(LL / 64, DD / 64, BB);
    transpose_dl<<<gc, 256, 0, stream>>>(ygT, ygTT);

    // output projection -> fp32 d_out; 256 wg, 8 waves
    gemm_bt_f32<<<(MM / 256) * (DD / 256), 512, 0, stream>>>(ygTT, Wo_bf, bo,
                                                             (float*)d_out, DD, DD);
}

// Round 11
// 549.017 us; speedup vs baseline: 1.0817x; 1.0145x over previous
//
#include <hip/hip_runtime.h>
#include <cstdint>
#include <cstddef>

#define DD 2048
#define LL 2048
#define BB 4
#define MM (BB * LL) // 8192
#define NN 6144      // fused q|k|v output columns

typedef __bf16 bf16;
typedef __bf16 bf16x8 __attribute__((ext_vector_type(8)));
typedef __bf16 bf16x4 __attribute__((ext_vector_type(4)));
typedef __bf16 bf16x2 __attribute__((ext_vector_type(2)));
typedef float f32x4 __attribute__((ext_vector_type(4)));

// ---------------------------------------------------------------------------
// async global -> LDS, 16B per lane (wave-uniform base + lane*16 layout)
// ---------------------------------------------------------------------------
__device__ __forceinline__ void gload16(const void* g, void* l) {
    __builtin_amdgcn_global_load_lds(
        (const __attribute__((address_space(1))) void*)g,
        (__attribute__((address_space(3))) void*)l, 16, 0, 0);
}

// ---------------------------------------------------------------------------
// fused fp32 -> bf16 conversion for all 5 tensors (1 launch).
// ---------------------------------------------------------------------------
__global__ __launch_bounds__(256) void cvt_all(
    const float* __restrict__ u, const float* __restrict__ wq,
    const float* __restrict__ wk, const float* __restrict__ wv,
    const float* __restrict__ wo, bf16* __restrict__ u_bf,
    bf16* __restrict__ wqkv, bf16* __restrict__ wo_bf) {
    const int blk = blockIdx.x;
    const float* s;
    bf16* d;
    int base;
    if (blk < 8192)       { s = u;  d = u_bf;            base = 0; }
    else if (blk < 10240) { s = wq; d = wqkv;            base = 8192; }
    else if (blk < 12288) { s = wk; d = wqkv + 4194304;  base = 10240; }
    else if (blk < 14336) { s = wv; d = wqkv + 8388608;  base = 12288; }
    else                  { s = wo; d = wo_bf;           base = 14336; }
    const int i = (blk - base) * 256 + threadIdx.x;
    const float4* sp = (const float4*)s + (size_t)i * 2;
    float4 a = sp[0], b = sp[1];
    bf16x8 o;
    o[0] = (bf16)a.x; o[1] = (bf16)a.y; o[2] = (bf16)a.z; o[3] = (bf16)a.w;
    o[4] = (bf16)b.x; o[5] = (bf16)b.y; o[6] = (bf16)b.z; o[7] = (bf16)b.w;
    *((bf16x8*)d + i) = o;
}

// ---------------------------------------------------------------------------
// 256x256 8-wave K-loop (BK=64, 2 LDS buffers = 128 KiB).
// R11: full m201-style phase structure -- 4 phases per K-tile, each phase
// {ds_reads ; stage 1 half-tile ; barrier ; lgkmcnt(0) ; setprio(1) ;
//  16 MFMA ; setprio(0) ; barrier}.  Counted vmcnt(4) at the END of Ph1
// (gates h1 of tile t) and Ph3 (gates h0 of tile t+1); never 0 until the
// last tile.  This activates T3's phase role-split (and thus T5 setprio).
// WAR safety: every stage's target region was last read >=4 barriers and
// one lgkm-draining MFMA earlier.
// ---------------------------------------------------------------------------
__device__ __forceinline__ void stage_half(const bf16* g, bf16* l, size_t rstep, int tid) {
    gload16(g, l + tid * 8);
    gload16(g + rstep, l + 4096 + tid * 8);
}

#define MFMA_BLK(AF, BQ, IOFF)                                                  \
    __builtin_amdgcn_s_setprio(1);                                              \
    _Pragma("unroll") for (int j = 0; j < 4; j++)                               \
        _Pragma("unroll") for (int i = 0; i < 4; i++)                           \
            acc[(IOFF) + i][j] = __builtin_amdgcn_mfma_f32_16x16x32_bf16(       \
                AF[i], BQ[j], acc[(IOFF) + i][j], 0, 0, 0);                     \
    __builtin_amdgcn_s_setprio(0);

template <int NT>
__device__ __forceinline__ void mma256_loop(const bf16* gA, const bf16* gB,
                                            int Kdim, bf16* lds,
                                            f32x4 (&acc)[8][4]) {
    const int tid = threadIdx.x;
    const int wave = tid >> 6, lane = tid & 63;
    const int wm = wave >> 2, wn = wave & 3;     // 2 x 4 wave grid
    const int fm = lane & 15, fg = lane >> 4;
    const size_t rstep = (size_t)128 * Kdim;
    const int koff = ((fg ^ ((fm >> 1) & 3)) << 3);
    const int aoff = (wm * 128 + fm) * 32 + koff;
    const int boff = (wn * 64 + fm) * 32 + koff;

    bf16* const A0 = lds;
    bf16* const B0 = lds + 32768;

#pragma unroll
    for (int i = 0; i < 8; i++)
#pragma unroll
        for (int j = 0; j < 4; j++) acc[i][j] = (f32x4){0.f, 0.f, 0.f, 0.f};

    // prologue: stage tile 0 fully (issue order = gate order)
    stage_half(gA, A0, rstep, tid);              // Ah0(0)
    stage_half(gB, B0, rstep, tid);              // Bh0(0)
    stage_half(gA + 32, A0 + 8192, rstep, tid);  // Ah1(0)
    stage_half(gB + 32, B0 + 8192, rstep, tid);  // Bh1(0)

    bf16x8 af0[4], af1[4], bq0[4], bq1[4];

    // gate tile-0 h0 (8 outstanding; wait oldest 4)
    asm volatile("s_waitcnt vmcnt(4)" ::: "memory");
    __builtin_amdgcn_s_barrier();

    for (int t = 0; t < NT; ++t) {
        const int c = t & 1;
        bf16* const Ac = A0 + c * 16384;
        bf16* const Bc = B0 + c * 16384;
        bf16* const An = A0 + (c ^ 1) * 16384;
        bf16* const Bn = B0 + (c ^ 1) * 16384;
        const bf16* a1 = gA + (t + 1) * 64;
        const bf16* b1 = gB + (t + 1) * 64;
        const bool st = (t + 1 < NT);

        // ---- Ph0: h0, A-rows i0-3 ----
#pragma unroll
        for (int i = 0; i < 4; i++) af0[i] = *(const bf16x8*)(Ac + aoff + i * 512);
#pragma unroll
        for (int j = 0; j < 4; j++) bq0[j] = *(const bf16x8*)(Bc + boff + j * 512);
        if (st) stage_half(a1, An, rstep, tid);          // Ah0(t+1)
        __builtin_amdgcn_s_barrier();
        asm volatile("s_waitcnt lgkmcnt(0)" ::: "memory");
        MFMA_BLK(af0, bq0, 0)
        __builtin_amdgcn_s_barrier();

        // ---- Ph1: h0, A-rows i4-7 ----
#pragma unroll
        for (int i = 0; i < 4; i++) af1[i] = *(const bf16x8*)(Ac + aoff + (i + 4) * 512);
        if (st) stage_half(b1, Bn, rstep, tid);          // Bh0(t+1)
        __builtin_amdgcn_s_barrier();
        asm volatile("s_waitcnt lgkmcnt(0)" ::: "memory");
        MFMA_BLK(af1, bq0, 4)
        // gate h1(t): outstanding = Ah1(t),Bh1(t) + Ah0(t+1),Bh0(t+1)
        if (st) { asm volatile("s_waitcnt vmcnt(4)" ::: "memory"); }
        else    { asm volatile("s_waitcnt vmcnt(0)" ::: "memory"); }
        __builtin_amdgcn_s_barrier();

        // ---- Ph2: h1, A-rows i0-3 ----
#pragma unroll
        for (int i = 0; i < 4; i++) af0[i] = *(const bf16x8*)(Ac + 8192 + aoff + i * 512);
#pragma unroll
        for (int j = 0; j < 4; j++) bq1[j] = *(const bf16x8*)(Bc + 8192 + boff + j * 512);
        if (st) stage_half(a1 + 32, An + 8192, rstep, tid); // Ah1(t+1)
        __builtin_amdgcn_s_barrier();
        asm volatile("s_waitcnt lgkmcnt(0)" ::: "memory");
        MFMA_BLK(af0, bq1, 0)
        __builtin_amdgcn_s_barrier();

        // ---- Ph3: h1, A-rows i4-7 ----
#pragma unroll
        for (int i = 0; i < 4; i++) af1[i] = *(const bf16x8*)(Ac + 8192 + aoff + (i + 4) * 512);
        if (st) stage_half(b1 + 32, Bn + 8192, rstep, tid); // Bh1(t+1)
        __builtin_amdgcn_s_barrier();
        asm volatile("s_waitcnt lgkmcnt(0)" ::: "memory");
        MFMA_BLK(af1, bq1, 4)
        // gate h0(t+1): outstanding = Ah0..Bh1(t+1) = 8; wait oldest 4
        if (st) { asm volatile("s_waitcnt vmcnt(4)" ::: "memory"); }
        __builtin_amdgcn_s_barrier();
    }
}

// ---------------------------------------------------------------------------
// Fused QKV GEMM -> transposed bf16 output (6144, 8192).  (epilogue unchanged)
// ---------------------------------------------------------------------------
__global__ __launch_bounds__(512, 2) void gemm_qkv(const bf16* __restrict__ A,
                                                   const bf16* __restrict__ Bm,
                                                   const float* __restrict__ bqp,
                                                   const float* __restrict__ bkp,
                                                   const float* __restrict__ bvp,
                                                   bf16* __restrict__ CtOut) {
    __shared__ bf16 lds[65536];
    const int id = blockIdx.x;        // nwg = 768 = 8 XCD x (4m x 24n)
    const int xcd = id & 7, li = id >> 3;
    const int m0 = (xcd * 4 + (li & 3)) << 8;
    const int n0 = (li >> 2) << 8;

    const int tid = threadIdx.x;
    const int wave = tid >> 6, lane = tid & 63;
    const int srow = tid >> 2;
    const int skx = (((lane & 3) ^ ((lane >> 3) & 3)) << 3);
    const bf16* gA = A + (size_t)(m0 + srow) * DD + skx;
    const bf16* gB = Bm + (size_t)(n0 + srow) * DD + skx;

    f32x4 acc[8][4];
    mma256_loop<DD / 64>(gA, gB, DD, lds, acc);

    __syncthreads();
    const int wm = wave >> 2, wn = wave & 3;
    const int fm = lane & 15, fg = lane >> 4;
    const float* bp = (n0 < 2048) ? bqp : ((n0 < 4096) ? bkp : bvp);
    const int nb = n0 & 2047;
#pragma unroll
    for (int j = 0; j < 4; j++) {
        const int col = wn * 64 + j * 16 + fm;
        const float bvv = bp[nb + col];
        const int csw = (col & 7) << 3;
#pragma unroll
        for (int i = 0; i < 8; i++) {
            const int row = (wm * 128 + i * 16 + fg * 4) ^ csw;
            bf16x4 o;
#pragma unroll
            for (int r = 0; r < 4; r++) o[r] = (bf16)(acc[i][j][r] + bvv);
            *(bf16x4*)&lds[col * 256 + row] = o;
        }
    }
    __syncthreads();
    const int ccol = tid >> 5, chunk = tid & 31;
#pragma unroll
    for (int p = 0; p < 16; p++) {
        const int col = p * 16 + ccol;
        bf16x8 vv = *(const bf16x8*)&lds[col * 256 + ((chunk * 8) ^ ((col & 7) << 3))];
        *(bf16x8*)(CtOut + (size_t)(n0 + col) * MM + m0 + chunk * 8) = vv;
    }
}

// ---------------------------------------------------------------------------
// Output projection GEMM (row-major f32 out).  (epilogue unchanged)
// ---------------------------------------------------------------------------
__global__ __launch_bounds__(512, 2) void gemm_bt_f32(const bf16* __restrict__ A,
                                                      const bf16* __restrict__ Bm,
                                                      const float* __restrict__ bias,
                                                      float* __restrict__ C,
                                                      int Ndim, int Kdim) {
    __shared__ bf16 lds[65536];
    const int id = blockIdx.x;
    const int xcd = id & 7, li = id >> 3;
    const int m0 = (xcd * 4 + (li & 3)) << 8;
    const int n0 = (li >> 2) << 8;

    const int tid = threadIdx.x;
    const int wave = tid >> 6, lane = tid & 63;
    const int srow = tid >> 2;
    const int skx = (((lane & 3) ^ ((lane >> 3) & 3)) << 3);
    const bf16* gA = A + (size_t)(m0 + srow) * Kdim + skx;
    const bf16* gB = Bm + (size_t)(n0 + srow) * Kdim + skx;

    f32x4 acc[8][4];
    mma256_loop<DD / 64>(gA, gB, Kdim, lds, acc);

    const int wm = wave >> 2, wn = wave & 3;
    const int fm = lane & 15, fg = lane >> 4;
#pragma unroll
    for (int j = 0; j < 4; j++) {
        const int col = n0 + wn * 64 + j * 16 + fm;
        const float bvv = bias[col];
#pragma unroll
        for (int i = 0; i < 8; i++) {
#pragma unroll
            for (int r = 0; r < 4; r++) {
                const int row = m0 + wm * 128 + i * 16 + fg * 4 + r;
                C[(size_t)row * Ndim + col] = acc[i][j][r] + bvv;
            }
        }
    }
}

// ---------------------------------------------------------------------------
// FUSED depthwise conv + causal long conv + D-skip + q gating.  (unchanged R10)
// ---------------------------------------------------------------------------
#define KVS 2112
__global__ __launch_bounds__(128, 2) void dwlc_gate(
    const bf16* __restrict__ qkvT,
    const float* __restrict__ cqw, const float* __restrict__ cqb,
    const float* __restrict__ ckw, const float* __restrict__ ckb,
    const float* __restrict__ kern, const float* __restrict__ Dskip,
    bf16* __restrict__ ygT) {
    __shared__ bf16 kv_ls[4 * KVS];
    __shared__ float krev_f[2112];
    const int d = blockIdx.x;
    const int tid = threadIdx.x;

    if (tid < 48) {
#pragma unroll
        for (int b2 = 0; b2 < 4; b2++) kv_ls[KVS * b2 + tid] = (bf16)0.f;
    } else if (tid < 64) {
#pragma unroll
        for (int b2 = 0; b2 < 4; b2++) kv_ls[KVS * b2 + 2048 + tid] = (bf16)0.f;
    }

    {
        const float* kr = kern + (size_t)d * LL;
#pragma unroll
        for (int c = 0; c < 16; ++c) {
            const int x = c * 128 + tid;
            krev_f[x] = kr[2047 - x];
        }
        if (tid < 64) krev_f[2048 + tid] = 0.f;
    }

    {
        const float k0 = ckw[d * 3], k1 = ckw[d * 3 + 1], k2 = ckw[d * 3 + 2];
        const float kb = ckb[d];
#pragma unroll
        for (int b = 0; b < 4; ++b) {
            const bf16* kR = qkvT + (size_t)(2048 + d) * MM + b * LL;
            const bf16* vR = qkvT + (size_t)(4096 + d) * MM + b * LL;
#pragma unroll
            for (int h = 0; h < 2; ++h) {
                const int l = tid * 16 + h * 8;
                bf16x8 kx = *(const bf16x8*)(kR + l);
                bf16x8 vx = *(const bf16x8*)(vR + l);
                float xk[10];
                xk[0] = 0.f; xk[1] = 0.f;
                if (l >= 2) {
                    bf16x2 kh = *(const bf16x2*)(kR + l - 2);
                    xk[0] = (float)kh[0]; xk[1] = (float)kh[1];
                }
#pragma unroll
                for (int c = 0; c < 8; c++) xk[c + 2] = (float)kx[c];
                bf16x8 okv;
#pragma unroll
                for (int c = 0; c < 8; c++) {
                    float kc = k0 * xk[c] + k1 * xk[c + 1] + k2 * xk[c + 2] + kb;
                    okv[c] = (bf16)(kc * (float)vx[c]);
                }
                *(bf16x8*)&kv_ls[KVS * b + 48 + l] = okv;
            }
        }
    }
    __syncthreads();

    const int lane = tid & 63;
    const int w = __builtin_amdgcn_readfirstlane(tid >> 6);
    const int n = lane & 15, q = lane >> 4;
    const int b = n & 3, pp = n >> 2;
    const int cB = KVS * b + 16 * pp + 8 * q;

    f32x4 acc[16];
#pragma unroll
    for (int s = 0; s < 16; s++) acc[s] = (f32x4){0.f, 0.f, 0.f, 0.f};

    for (int it = 0; it < 64; ++it) {
        const int as = 2031 - 32 * it - n + 8 * q;
        float af[8];
#pragma unroll
        for (int j = 0; j < 8; j++) af[j] = krev_f[as + j];
        bf16x8 a;
#pragma unroll
        for (int j = 0; j < 8; j++) a[j] = (bf16)af[j];

        const int bbase = cB + 64 * w + 32 - 32 * it;
#pragma unroll
        for (int h = 0; h < 2; ++h) {
            bf16x8 bfr[8];
#pragma unroll
            for (int s8 = 0; s8 < 8; s8++) {
                const int s = h * 8 + s8;
                if (it <= 4 * s + 2 * w + 1)
                    bfr[s8] = *(const bf16x8*)&kv_ls[bbase + 128 * s];
            }
#pragma unroll
            for (int s8 = 0; s8 < 8; s8++) {
                const int s = h * 8 + s8;
                if (it <= 4 * s + 2 * w + 1)
                    acc[s] = __builtin_amdgcn_mfma_f32_16x16x32_bf16(
                        a, bfr[s8], acc[s], 0, 0, 0);
            }
        }
    }

    const float q0 = cqw[d * 3], q1 = cqw[d * 3 + 1], q2 = cqw[d * 3 + 2];
    const float qb = cqb[d];
    const float dsk = Dskip[d];
    const bf16* qR = qkvT + (size_t)d * MM + b * LL;
#pragma unroll
    for (int s = 0; s < 16; s++) {
        const int i = 2 * s + w;
        const int l = 64 * i + 16 * pp + 4 * q;
        const size_t gb = ((size_t)b * DD + d) * LL + l;
        bf16x4 cx = *(const bf16x4*)&qR[l];
        bf16x4 hx;
        if (l >= 4) hx = *(const bf16x4*)&qR[l - 4];
        else { hx[0] = (bf16)0.f; hx[1] = (bf16)0.f; hx[2] = (bf16)0.f; hx[3] = (bf16)0.f; }
        float x2[6] = { (float)hx[2], (float)hx[3], (float)cx[0],
                        (float)cx[1], (float)cx[2], (float)cx[3] };
        bf16x4 kv4 = *(const bf16x4*)&kv_ls[KVS * b + 48 + l];
        bf16x4 o;
#pragma unroll
        for (int r = 0; r < 4; r++) {
            const float qc = q0 * x2[r] + q1 * x2[r + 1] + q2 * x2[r + 2] + qb;
            const float val = (acc[s][r] + (float)kv4[r] * dsk) * qc;
            o[r] = (bf16)val;
        }
        *(bf16x4*)&ygT[gb] = o;
    }
}

// ---------------------------------------------------------------------------
// bf16 transpose (B, D, L) -> (B, L, D), 64x64 tiles, fully vectorized.
// ---------------------------------------------------------------------------
__global__ __launch_bounds__(256) void transpose_dl(const bf16* __restrict__ src,
                                                    bf16* __restrict__ dst) {
    __shared__ bf16 ts[64 * 64];
    const int b = blockIdx.z;
    const int l0 = blockIdx.x * 64, d0 = blockIdx.y * 64;
    const int tid = threadIdx.x;
    {
        const int r0 = tid >> 3, c8 = tid & 7;
#pragma unroll
        for (int h = 0; h < 2; h++) {
            const int r = r0 + h * 32;
            bf16x8 v = *(const bf16x8*)&src[((size_t)b * DD + d0 + r) * LL + l0 + c8 * 8];
            *(bf16x8*)&ts[r * 64 + ((c8 ^ (r & 7)) << 3)] = v;
        }
    }
    __syncthreads();
    const int l = tid & 63, dc0 = (tid >> 6) << 3;
#pragma unroll
    for (int half = 0; half < 2; half++) {
        const int dc = dc0 + half * 32;
        bf16x8 o;
#pragma unroll
        for (int j = 0; j < 8; j++) {
            const int r = dc + j;
            o[j] = ts[r * 64 + (((l >> 3) ^ (r & 7)) << 3) + (l & 7)];
        }
        *(bf16x8*)&dst[((size_t)b * LL + l0 + l) * DD + d0 + dc] = o;
    }
}

// ---------------------------------------------------------------------------
// launch
// ---------------------------------------------------------------------------
extern "C" void kernel_launch(void* const* d_in, const int* in_sizes, int n_in,
                              void* d_out, int out_size, void* d_ws, size_t ws_size,
                              hipStream_t stream) {
    const float* u   = (const float*)d_in[0];
    const float* Wq  = (const float*)d_in[1];
    const float* bq  = (const float*)d_in[2];
    const float* Wk  = (const float*)d_in[3];
    const float* bk  = (const float*)d_in[4];
    const float* Wv  = (const float*)d_in[5];
    const float* bv  = (const float*)d_in[6];
    const float* cqw = (const float*)d_in[7];
    const float* cqb = (const float*)d_in[8];
    const float* ckw = (const float*)d_in[9];
    const float* ckb = (const float*)d_in[10];
    const float* ssm = (const float*)d_in[11];
    const float* Dsk = (const float*)d_in[12];
    const float* Wo  = (const float*)d_in[13];
    const float* bo  = (const float*)d_in[14];

    char* w = (char*)d_ws;
    bf16* u_bf    = (bf16*)(w);                  // 33.55 MB (reused as ygT)
    bf16* Wqkv_bf = (bf16*)(w + 33554432ull);    // 25.2 MB (q|k|v rows concat)
    bf16* Wo_bf   = (bf16*)(w + 58720256ull);    // 8.39 MB
    bf16* qkvT    = (bf16*)(w + 67108864ull);    // 100.7 MB (6144 x 8192)

    // fused fp32 -> bf16 conversions (u, Wq|Wk|Wv, Wo) in one launch
    cvt_all<<<16384, 256, 0, stream>>>(u, Wq, Wk, Wv, Wo, u_bf, Wqkv_bf, Wo_bf);

    // fused q/k/v projection -> transposed output (E, B*L); 768 wg, 8 waves
    gemm_qkv<<<(MM / 256) * (NN / 256), 512, 0, stream>>>(u_bf, Wqkv_bf, bq, bk, bv, qkvT);

    // fused depthwise convs + causal long conv (Toeplitz MFMA) + gating
    bf16* ygT = u_bf; // reuse
    dwlc_gate<<<DD, 128, 0, stream>>>(qkvT, cqw, cqb, ckw, ckb, ssm, Dsk, ygT);

    // transpose back to (B,L,E)
    bf16* ygTT = qkvT; // reuse
    dim3 gc(LL / 64, DD / 64, BB);
    transpose_dl<<<gc, 256, 0, stream>>>(ygT, ygTT);

    // output projection -> fp32 d_out; 256 wg, 8 waves
    gemm_bt_f32<<<(MM / 256) * (DD / 256), 512, 0, stream>>>(ygTT, Wo_bf, bo,
                                                             (float*)d_out, DD, DD);
}